// Round 2
// baseline (1631.894 us; speedup 1.0000x reference)
//
#include <hip/hip_runtime.h>

#define N 8192
#define NROW 16                 // rows per fused block
#define NBLK (N / NROW)         // 512 fused blocks

// Online LSE update with a single exp: state (m, s), new value v.
__device__ __forceinline__ void olse(float& m, float& s, float v)
{
    const float d = v - m;
    const float e = __expf(-fabsf(d));
    if (d > 0.f) { m = v; s = __fmaf_rn(s, e, 1.f); }
    else         { s = s + e; }
}

// ---------------------------------------------------------------------------
// Fused pass: for a chunk of NROW rows, compute r[i] = LSE_j(A[i][j]-c[j])
// (full row held in registers, block-wide two-sweep LSE), then immediately
// fold the row into per-column online LSE of (A[i][j] - r[i]).
// Thread t owns columns {4*(t + k*256) .. +3} for k=0..7 (coalesced float4).
// Emits one partial column-LSE vector pl[blk][j] = m_j + log(s_j).
// ---------------------------------------------------------------------------
__global__ __launch_bounds__(256, 2) void fused_pass_kernel(
    const float* __restrict__ A,
    const float* __restrict__ c,
    float* __restrict__ r,
    float* __restrict__ pl,     // [NBLK][N]
    int use_c)
{
    const int t    = threadIdx.x;
    const int blk  = blockIdx.x;
    const int row0 = blk * NROW;

    const float4* __restrict__ c4 = (const float4*)c;

    float4 cc[8];
#pragma unroll
    for (int k = 0; k < 8; ++k) {
        if (use_c) cc[k] = c4[t + (k << 8)];
        else       cc[k] = make_float4(0.f, 0.f, 0.f, 0.f);
    }

    float4 colm[8], cols[8];
#pragma unroll
    for (int k = 0; k < 8; ++k) {
        colm[k] = make_float4(-1e30f, -1e30f, -1e30f, -1e30f);
        cols[k] = make_float4(0.f, 0.f, 0.f, 0.f);
    }

    __shared__ float smax[4];
    __shared__ float ssum[4];
    const int wave = t >> 6;

    for (int i = 0; i < NROW; ++i) {
        const float4* __restrict__ Ar = (const float4*)(A + (size_t)(row0 + i) * N);
        float4 v[8];
#pragma unroll
        for (int k = 0; k < 8; ++k) v[k] = Ar[t + (k << 8)];

        // --- block-wide max of (v - cc) ---
        float m = -1e30f;
#pragma unroll
        for (int k = 0; k < 8; ++k) {
            m = fmaxf(m, fmaxf(fmaxf(v[k].x - cc[k].x, v[k].y - cc[k].y),
                               fmaxf(v[k].z - cc[k].z, v[k].w - cc[k].w)));
        }
#pragma unroll
        for (int off = 32; off > 0; off >>= 1)
            m = fmaxf(m, __shfl_xor(m, off));
        if ((t & 63) == 0) smax[wave] = m;
        __syncthreads();
        m = fmaxf(fmaxf(smax[0], smax[1]), fmaxf(smax[2], smax[3]));

        // --- block-wide sum of exp(v - cc - m) ---
        float s = 0.f;
#pragma unroll
        for (int k = 0; k < 8; ++k) {
            s += __expf(v[k].x - cc[k].x - m);
            s += __expf(v[k].y - cc[k].y - m);
            s += __expf(v[k].z - cc[k].z - m);
            s += __expf(v[k].w - cc[k].w - m);
        }
#pragma unroll
        for (int off = 32; off > 0; off >>= 1)
            s += __shfl_xor(s, off);
        if ((t & 63) == 0) ssum[wave] = s;
        __syncthreads();
        const float ri = m + __logf(ssum[0] + ssum[1] + ssum[2] + ssum[3]);
        if (t == 0) r[row0 + i] = ri;

        // --- fold row into per-column online LSE of (v - ri) ---
#pragma unroll
        for (int k = 0; k < 8; ++k) {
            olse(colm[k].x, cols[k].x, v[k].x - ri);
            olse(colm[k].y, cols[k].y, v[k].y - ri);
            olse(colm[k].z, cols[k].z, v[k].z - ri);
            olse(colm[k].w, cols[k].w, v[k].w - ri);
        }
    }

    float4* __restrict__ pl4 = (float4*)(pl + (size_t)blk * N);
#pragma unroll
    for (int k = 0; k < 8; ++k) {
        float4 p;
        p.x = colm[k].x + __logf(cols[k].x);
        p.y = colm[k].y + __logf(cols[k].y);
        p.z = colm[k].z + __logf(cols[k].z);
        p.w = colm[k].w + __logf(cols[k].w);
        pl4[t + (k << 8)] = p;
    }
}

// ---------------------------------------------------------------------------
// Combine NBLK partial column LSEs per column: c[j] = LSE_k(pl[k][j]).
// Two-sweep (max then sum); second sweep hits L2.
// ---------------------------------------------------------------------------
__global__ __launch_bounds__(256) void col_reduce_kernel(const float* __restrict__ pl,
                                                         float* __restrict__ c)
{
    const int col = blockIdx.x * 256 + threadIdx.x;
    float M = -1e30f;
#pragma unroll 16
    for (int k = 0; k < NBLK; ++k)
        M = fmaxf(M, pl[(size_t)k * N + col]);
    float S = 0.f;
#pragma unroll 16
    for (int k = 0; k < NBLK; ++k)
        S += __expf(pl[(size_t)k * N + col] - M);
    c[col] = M + __logf(S);
}

// ---------------------------------------------------------------------------
// Final: out[i][j] = exp(A[i][j] - r[i] - c[j])
// ---------------------------------------------------------------------------
__global__ __launch_bounds__(256) void finalize_kernel(const float* __restrict__ A,
                                                       const float* __restrict__ r,
                                                       const float* __restrict__ c,
                                                       float* __restrict__ out)
{
    const int row = blockIdx.x;
    const int t   = threadIdx.x;
    const float rr = r[row];
    const float4* __restrict__ Ar = (const float4*)(A + (size_t)row * N);
    const float4* __restrict__ c4 = (const float4*)c;
    float4* __restrict__ Or = (float4*)(out + (size_t)row * N);
#pragma unroll
    for (int k = 0; k < 8; ++k) {
        const int idx = t + (k << 8);
        float4 a  = Ar[idx];
        float4 cc = c4[idx];
        float4 o;
        o.x = __expf(a.x - rr - cc.x);
        o.y = __expf(a.y - rr - cc.y);
        o.z = __expf(a.z - rr - cc.z);
        o.w = __expf(a.w - rr - cc.w);
        Or[idx] = o;
    }
}

extern "C" void kernel_launch(void* const* d_in, const int* in_sizes, int n_in,
                              void* d_out, int out_size, void* d_ws, size_t ws_size,
                              hipStream_t stream)
{
    const float* A = (const float*)d_in[0];
    float* out = (float*)d_out;

    // r, c in workspace (64 KB).
    float* r = (float*)d_ws;             // N floats
    float* c = r + N;                    // N floats

    // Partial column LSEs live in d_out scratch (NBLK*N*4 = 16 MB out of
    // 256 MB); finalize_kernel fully overwrites d_out afterwards.
    float* pl = out;

    for (int it = 0; it < 10; ++it) {
        hipLaunchKernelGGL(fused_pass_kernel, dim3(NBLK), dim3(256), 0, stream,
                           A, c, r, pl, it /* use_c: 0 on first iteration */);
        hipLaunchKernelGGL(col_reduce_kernel, dim3(N / 256), dim3(256), 0, stream,
                           pl, c);
    }
    hipLaunchKernelGGL(finalize_kernel, dim3(N), dim3(256), 0, stream, A, r, c, out);
}

// Round 3
// 1286.954 us; speedup vs baseline: 1.2680x; 1.2680x over previous
//
#include <hip/hip_runtime.h>

#define N 8192
#define TPB 1024
#define NW (TPB / 64)            // 16 waves per block
#define ROWS_PER_BLK 32
#define NBLK (N / ROWS_PER_BLK)  // 256 blocks == 1 per CU
#define RB 4                     // rows per batch (one barrier per batch)

// Online LSE update with a single exp: state (m, s), new value v.
__device__ __forceinline__ void olse(float& m, float& s, float v)
{
    const float d = v - m;
    const float e = __expf(-fabsf(d));
    if (d > 0.f) { m = v; s = __fmaf_rn(s, e, 1.f); }
    else         { s = s + e; }
}

// ---------------------------------------------------------------------------
// Fused pass over a 32-row chunk:
//   r[i] = LSE_j(A[i][j] - c[j])  (block-wide, batched 4 rows per barrier)
//   then fold each row into per-column online LSE of (A[i][j] - r[i]),
//   emitting partial column LSE pl[blk][j] = m_j + log(s_j).
// Thread t owns columns {4t..4t+3} and {4096+4t..4096+4t+3} (coalesced).
// ---------------------------------------------------------------------------
__global__ __launch_bounds__(TPB, 4) void fused_pass_kernel(
    const float* __restrict__ A,
    const float* __restrict__ c,
    float* __restrict__ r,
    float* __restrict__ pl,     // [NBLK][N]
    int use_c)
{
    const int t    = threadIdx.x;
    const int lane = t & 63;
    const int wave = t >> 6;
    const int blk  = blockIdx.x;
    const int row0 = blk * ROWS_PER_BLK;

    const float4* __restrict__ c4 = (const float4*)c;
    float4 cc0, cc1;
    if (use_c) { cc0 = c4[t]; cc1 = c4[t + TPB]; }
    else {
        cc0 = make_float4(0.f, 0.f, 0.f, 0.f);
        cc1 = make_float4(0.f, 0.f, 0.f, 0.f);
    }

    // per-column online-LSE state (8 columns per thread)
    float4 colm0 = make_float4(-1e30f, -1e30f, -1e30f, -1e30f);
    float4 colm1 = colm0;
    float4 cols0 = make_float4(0.f, 0.f, 0.f, 0.f);
    float4 cols1 = cols0;

    __shared__ float lm[2][RB][NW];   // double-buffered wave partials
    __shared__ float ls[2][RB][NW];

    for (int it = 0; it < ROWS_PER_BLK / RB; ++it) {
        const int buf = it & 1;
        const int rbase = row0 + it * RB;

        // --- load 4 rows (8 floats each per thread) ---
        float4 v0[RB], v1[RB];
#pragma unroll
        for (int rr = 0; rr < RB; ++rr) {
            const float4* __restrict__ Ar = (const float4*)(A + (size_t)(rbase + rr) * N);
            v0[rr] = Ar[t];
            v1[rr] = Ar[t + TPB];
        }

        // --- per-thread two-sweep partial LSE of (v - cc) per row ---
        float tm[RB], ts[RB];
#pragma unroll
        for (int rr = 0; rr < RB; ++rr) {
            const float w0 = v0[rr].x - cc0.x, w1 = v0[rr].y - cc0.y;
            const float w2 = v0[rr].z - cc0.z, w3 = v0[rr].w - cc0.w;
            const float w4 = v1[rr].x - cc1.x, w5 = v1[rr].y - cc1.y;
            const float w6 = v1[rr].z - cc1.z, w7 = v1[rr].w - cc1.w;
            float m = fmaxf(fmaxf(fmaxf(w0, w1), fmaxf(w2, w3)),
                            fmaxf(fmaxf(w4, w5), fmaxf(w6, w7)));
            float s = __expf(w0 - m) + __expf(w1 - m) + __expf(w2 - m) + __expf(w3 - m)
                    + __expf(w4 - m) + __expf(w5 - m) + __expf(w6 - m) + __expf(w7 - m);
            tm[rr] = m;
            ts[rr] = s;
        }

        // --- wave reduce (no barrier): max, then scaled sum ---
#pragma unroll
        for (int rr = 0; rr < RB; ++rr) {
            float M = tm[rr];
#pragma unroll
            for (int off = 32; off > 0; off >>= 1)
                M = fmaxf(M, __shfl_xor(M, off));
            float S = ts[rr] * __expf(tm[rr] - M);
#pragma unroll
            for (int off = 32; off > 0; off >>= 1)
                S += __shfl_xor(S, off);
            if (lane == 0) { lm[buf][rr][wave] = M; ls[buf][rr][wave] = S; }
        }
        __syncthreads();

        // --- every thread combines the 16 wave partials (LDS broadcast) ---
        float rfin[RB];
#pragma unroll
        for (int rr = 0; rr < RB; ++rr) {
            float M = lm[buf][rr][0];
#pragma unroll
            for (int w = 1; w < NW; ++w) M = fmaxf(M, lm[buf][rr][w]);
            float S = 0.f;
#pragma unroll
            for (int w = 0; w < NW; ++w) S += ls[buf][rr][w] * __expf(lm[buf][rr][w] - M);
            rfin[rr] = M + __logf(S);
        }
        if (t < RB) r[rbase + t] = rfin[t];

        // --- fold rows into per-column online LSE of (v - rfin) ---
#pragma unroll
        for (int rr = 0; rr < RB; ++rr) {
            const float ri = rfin[rr];
            olse(colm0.x, cols0.x, v0[rr].x - ri);
            olse(colm0.y, cols0.y, v0[rr].y - ri);
            olse(colm0.z, cols0.z, v0[rr].z - ri);
            olse(colm0.w, cols0.w, v0[rr].w - ri);
            olse(colm1.x, cols1.x, v1[rr].x - ri);
            olse(colm1.y, cols1.y, v1[rr].y - ri);
            olse(colm1.z, cols1.z, v1[rr].z - ri);
            olse(colm1.w, cols1.w, v1[rr].w - ri);
        }
        // no second barrier: LDS partials are double-buffered
    }

    float4* __restrict__ pl4 = (float4*)(pl + (size_t)blk * N);
    float4 p;
    p.x = colm0.x + __logf(cols0.x);
    p.y = colm0.y + __logf(cols0.y);
    p.z = colm0.z + __logf(cols0.z);
    p.w = colm0.w + __logf(cols0.w);
    pl4[t] = p;
    p.x = colm1.x + __logf(cols1.x);
    p.y = colm1.y + __logf(cols1.y);
    p.z = colm1.z + __logf(cols1.z);
    p.w = colm1.w + __logf(cols1.w);
    pl4[t + TPB] = p;
}

// ---------------------------------------------------------------------------
// Combine NBLK partial column LSEs per column: c[j] = LSE_k(pl[k][j]).
// ---------------------------------------------------------------------------
__global__ __launch_bounds__(256) void col_reduce_kernel(const float* __restrict__ pl,
                                                         float* __restrict__ c)
{
    const int col = blockIdx.x * 256 + threadIdx.x;
    float M = -1e30f;
#pragma unroll 8
    for (int k = 0; k < NBLK; ++k)
        M = fmaxf(M, pl[(size_t)k * N + col]);
    float S = 0.f;
#pragma unroll 8
    for (int k = 0; k < NBLK; ++k)
        S += __expf(pl[(size_t)k * N + col] - M);
    c[col] = M + __logf(S);
}

// ---------------------------------------------------------------------------
// Final: out[i][j] = exp(A[i][j] - r[i] - c[j])
// ---------------------------------------------------------------------------
__global__ __launch_bounds__(256) void finalize_kernel(const float* __restrict__ A,
                                                       const float* __restrict__ r,
                                                       const float* __restrict__ c,
                                                       float* __restrict__ out)
{
    const int row = blockIdx.x;
    const int t   = threadIdx.x;
    const float rr = r[row];
    const float4* __restrict__ Ar = (const float4*)(A + (size_t)row * N);
    const float4* __restrict__ c4 = (const float4*)c;
    float4* __restrict__ Or = (float4*)(out + (size_t)row * N);
#pragma unroll
    for (int k = 0; k < 8; ++k) {
        const int idx = t + (k << 8);
        float4 a  = Ar[idx];
        float4 cc = c4[idx];
        float4 o;
        o.x = __expf(a.x - rr - cc.x);
        o.y = __expf(a.y - rr - cc.y);
        o.z = __expf(a.z - rr - cc.z);
        o.w = __expf(a.w - rr - cc.w);
        Or[idx] = o;
    }
}

extern "C" void kernel_launch(void* const* d_in, const int* in_sizes, int n_in,
                              void* d_out, int out_size, void* d_ws, size_t ws_size,
                              hipStream_t stream)
{
    const float* A = (const float*)d_in[0];
    float* out = (float*)d_out;

    // r, c in workspace (64 KB).
    float* r = (float*)d_ws;             // N floats
    float* c = r + N;                    // N floats

    // Partial column LSEs live in d_out scratch (NBLK*N*4 = 8 MB out of
    // 256 MB); finalize_kernel fully overwrites d_out afterwards.
    float* pl = out;

    for (int it = 0; it < 10; ++it) {
        hipLaunchKernelGGL(fused_pass_kernel, dim3(NBLK), dim3(TPB), 0, stream,
                           A, c, r, pl, it /* use_c: 0 on first iteration */);
        hipLaunchKernelGGL(col_reduce_kernel, dim3(N / 256), dim3(256), 0, stream,
                           pl, c);
    }
    hipLaunchKernelGGL(finalize_kernel, dim3(N), dim3(256), 0, stream, A, r, c, out);
}